// Round 4
// baseline (299.294 us; speedup 1.0000x reference)
//
#include <hip/hip_runtime.h>
#include <stdint.h>

#define MDIM 4096
#define NDIM 4096
#define KDIM 4096

#define BM 256
#define BN 256
#define BK 64
#define NT (KDIM / BK)   // 64 K-tiles

typedef __attribute__((ext_vector_type(8))) __bf16 bf16x8;
typedef __attribute__((ext_vector_type(16))) float f32x16;
typedef __attribute__((ext_vector_type(8))) unsigned short ushort8_t;
typedef __attribute__((ext_vector_type(4))) unsigned short ushort4_t;

typedef const __attribute__((address_space(1))) void* gas_ptr;
typedef __attribute__((address_space(3))) void* las_ptr;

__device__ __forceinline__ void async_load16(const void* g, void* l) {
    __builtin_amdgcn_global_load_lds((gas_ptr)g, (las_ptr)l, 16, 0, 0);
}

__device__ __forceinline__ unsigned short f32_to_bf16_rne(float f) {
    union { float f; uint32_t u; } v; v.f = f;
    uint32_t u = v.u;
    return (unsigned short)((u + 0x7FFFu + ((u >> 16) & 1u)) >> 16);
}

__device__ __forceinline__ unsigned short sgn_bf16(float w) {
    return (w > 0.f) ? 0x3F80u : ((w < 0.f) ? 0xBF80u : 0u);
}

// ---------------- prep kernels (split for rocprof visibility) ----------------

#define XBLKS 2048

__global__ void prep_x(const float* __restrict__ x, unsigned short* __restrict__ xbf) {
    const int tot8 = MDIM * KDIM / 8;
    int t = blockIdx.x * 256 + threadIdx.x;
    const int stride = XBLKS * 256;
    for (int i = t; i < tot8; i += stride) {
        float4 v0 = ((const float4*)x)[2 * i];
        float4 v1 = ((const float4*)x)[2 * i + 1];
        ushort8_t o;
        o[0] = f32_to_bf16_rne(v0.x); o[1] = f32_to_bf16_rne(v0.y);
        o[2] = f32_to_bf16_rne(v0.z); o[3] = f32_to_bf16_rne(v0.w);
        o[4] = f32_to_bf16_rne(v1.x); o[5] = f32_to_bf16_rne(v1.y);
        o[6] = f32_to_bf16_rne(v1.z); o[7] = f32_to_bf16_rne(v1.w);
        ((ushort8_t*)xbf)[i] = o;
    }
}

// W[k][n] -> sign -> bf16, transposed to WqT[n][k] via LDS tile (pad 68).
__global__ void prep_w(const float* __restrict__ W, unsigned short* __restrict__ wqT) {
    __shared__ __align__(16) unsigned short tile[64][68];   // [n][k]
    const int wb = blockIdx.x;
    const int n0 = (wb & 63) * 64;
    const int k0 = (wb >> 6) * 64;
    const int t  = threadIdx.x;
#pragma unroll
    for (int r = 0; r < 2; ++r) {
        int flat = r * 256 + t;
        int k2   = flat >> 4;
        int nch  = (flat & 15) * 4;
        const float* s0 = &W[(size_t)(k0 + 2 * k2) * NDIM + n0 + nch];
        float4 v0 = *(const float4*)(s0);
        float4 v1 = *(const float4*)(s0 + NDIM);
        const float* f0 = (const float*)&v0;
        const float* f1 = (const float*)&v1;
#pragma unroll
        for (int j = 0; j < 4; ++j) {
            union { unsigned short u[2]; unsigned int w; } p;
            p.u[0] = sgn_bf16(f0[j]);
            p.u[1] = sgn_bf16(f1[j]);
            *(unsigned int*)&tile[nch + j][2 * k2] = p.w;
        }
    }
    __syncthreads();
#pragma unroll
    for (int r = 0; r < 2; ++r) {
        int flat = r * 256 + t;
        int n    = flat >> 3;
        int kch  = (flat & 7) * 8;
        ushort4_t a = *(const ushort4_t*)&tile[n][kch];
        ushort4_t b = *(const ushort4_t*)&tile[n][kch + 4];
        ushort8_t o;
        o[0] = a[0]; o[1] = a[1]; o[2] = a[2]; o[3] = a[3];
        o[4] = b[0]; o[5] = b[1]; o[6] = b[2]; o[7] = b[3];
        *(ushort8_t*)&wqT[(size_t)(n0 + n) * KDIM + k0 + kch] = o;
    }
}

// ---- GEMM: 256x256, 8 waves, mfma_f32_32x32x16_bf16, counted-vmcnt pipeline ----
// R2 pipeline intact: both-sides XOR swizzle, 4 phases/tile, 2 barriers/phase,
// boundary vmcnt(8) (never 0 steady-state). New: 32x32x16 MFMA (8/phase), C stores
// cover full 128B lines, staging split B->ph2 / A->ph3.

__global__ __launch_bounds__(512, 2) void gemm_bf16_bt(
        const unsigned short* __restrict__ A,
        const unsigned short* __restrict__ Bt,
        const float* __restrict__ bias,
        float* __restrict__ C)
{
    __shared__ __align__(16) unsigned short lds[2][2][BM * BK];  // [buf][A/B]

    const int tid  = threadIdx.x;
    const int wave = tid >> 6;
    const int lane = tid & 63;
    const int wm = wave >> 2;           // 0..1 -> 128 rows
    const int wn = wave & 3;            // 0..3 -> 64 cols

    // XCD-bijective swizzle: each XCD owns a 4x8 rect of tiles
    int o   = blockIdx.y * gridDim.x + blockIdx.x;
    int xcd = o & 7, ii = o >> 3;
    int bmi = (xcd >> 1) * 4 + (ii >> 3);
    int bni = (xcd & 1) * 8 + (ii & 7);
    const int bm = bmi * BM;
    const int bn = bni * BN;

    // staging: group g (8 rows) -> LDS bytes g*1024 linear; lane l: row=l>>3,
    // source chunk = (l&7) ^ row  (pre-swizzled source, linear dest)
    const int lrow = lane >> 3;
    const int lchk = (lane & 7) ^ lrow;
    const size_t aSrc = (size_t)(bm + lrow) * KDIM + lchk * 8;
    const size_t bSrc = (size_t)(bn + lrow) * KDIM + lchk * 8;
    const int g0 = wave * 4;

#define STAGE_A(BUF, TK, G) async_load16(A  + aSrc + (size_t)(G) * (8 * KDIM) + (TK), \
                                         &lds[BUF][0][(G) * 512])
#define STAGE_B(BUF, TK, G) async_load16(Bt + bSrc + (size_t)(G) * (8 * KDIM) + (TK), \
                                         &lds[BUF][1][(G) * 512])

    // fragment reads (XOR-swizzled), 32x32x16:
    // row = 32*mf + (lane&31), k = s*16 + (lane>>5)*8 + j, s=0..3
    // byte = row*128 + ((2s + (lane>>5)) ^ (row&7))*16, row&7 == lane&7
    const int l31  = lane & 31;
    const int base0 = l31 * 128 + ((((lane >> 5) ^ lane) & 1) << 4);
    const int q2   = (lane >> 1) & 3;
    const int oa0 = wm * 16384 + base0 + ((0 ^ q2) << 5);
    const int oa1 = wm * 16384 + base0 + ((1 ^ q2) << 5);
    const int oa2 = wm * 16384 + base0 + ((2 ^ q2) << 5);
    const int oa3 = wm * 16384 + base0 + ((3 ^ q2) << 5);
    const int ob0 = 32768 + wn * 8192 + base0 + ((0 ^ q2) << 5);
    const int ob1 = 32768 + wn * 8192 + base0 + ((1 ^ q2) << 5);
    const int ob2 = 32768 + wn * 8192 + base0 + ((2 ^ q2) << 5);
    const int ob3 = 32768 + wn * 8192 + base0 + ((3 ^ q2) << 5);

    const char* L = (const char*)lds;

    f32x16 acc[4][2] = {};
    bf16x8 af[2][4];
    bf16x8 bf[2][4];

#define MFMA_PH(IA, NF)                                                         \
    _Pragma("unroll")                                                           \
    for (int s = 0; s < 4; ++s)                                                 \
        _Pragma("unroll")                                                       \
        for (int i = 0; i < 2; ++i)                                             \
            acc[(IA) + i][NF] = __builtin_amdgcn_mfma_f32_32x32x16_bf16(        \
                af[i][s], bf[NF][s], acc[(IA) + i][NF], 0, 0, 0);

#define STAGE_HALF_B(BUF, TK)                                    \
    do {                                                         \
        STAGE_B(BUF, TK, g0 + 0); STAGE_B(BUF, TK, g0 + 1);      \
        STAGE_B(BUF, TK, g0 + 2); STAGE_B(BUF, TK, g0 + 3);      \
    } while (0)
#define STAGE_HALF_A(BUF, TK)                                    \
    do {                                                         \
        STAGE_A(BUF, TK, g0 + 0); STAGE_A(BUF, TK, g0 + 1);      \
        STAGE_A(BUF, TK, g0 + 2); STAGE_A(BUF, TK, g0 + 3);      \
    } while (0)

    // prologue: tile0 -> buf0, tile1 -> buf1; wait only tile0's 8 loads
    STAGE_HALF_B(0, 0);  STAGE_HALF_A(0, 0);
    STAGE_HALF_B(1, BK); STAGE_HALF_A(1, BK);
    asm volatile("s_waitcnt vmcnt(8)" ::: "memory");
    __builtin_amdgcn_s_barrier();
    asm volatile("" ::: "memory");
    __builtin_amdgcn_sched_barrier(0);

    for (int t = 0; t < NT; ++t) {
        const int bofs = (t & 1) << 16;
        const char* A0 = L + bofs + oa0; const char* A1 = L + bofs + oa1;
        const char* A2 = L + bofs + oa2; const char* A3 = L + bofs + oa3;
        const char* B0 = L + bofs + ob0; const char* B1 = L + bofs + ob1;
        const char* B2 = L + bofs + ob2; const char* B3 = L + bofs + ob3;
        const int cur = t & 1;
        const int tkn = (t + 2) * BK;
        const bool more = (t + 2 < NT);

        // phase 0: read af(mf0,1)+bf[0]; MFMA acc[0..1][0]
#pragma unroll
        for (int i = 0; i < 2; ++i) {
            af[i][0] = *(const bf16x8*)(A0 + i * 4096);
            af[i][1] = *(const bf16x8*)(A1 + i * 4096);
            af[i][2] = *(const bf16x8*)(A2 + i * 4096);
            af[i][3] = *(const bf16x8*)(A3 + i * 4096);
        }
        bf[0][0] = *(const bf16x8*)(B0);
        bf[0][1] = *(const bf16x8*)(B1);
        bf[0][2] = *(const bf16x8*)(B2);
        bf[0][3] = *(const bf16x8*)(B3);
        __builtin_amdgcn_s_barrier();
        __builtin_amdgcn_s_setprio(1);
        MFMA_PH(0, 0)
        __builtin_amdgcn_s_setprio(0);
        __builtin_amdgcn_s_barrier();

        // phase 1: read bf[1]; MFMA acc[0..1][1]
        bf[1][0] = *(const bf16x8*)(B0 + 4096);
        bf[1][1] = *(const bf16x8*)(B1 + 4096);
        bf[1][2] = *(const bf16x8*)(B2 + 4096);
        bf[1][3] = *(const bf16x8*)(B3 + 4096);
        __builtin_amdgcn_s_barrier();
        __builtin_amdgcn_s_setprio(1);
        MFMA_PH(0, 1)
        __builtin_amdgcn_s_setprio(0);
        __builtin_amdgcn_s_barrier();
        // B-region of buf[cur] read-free from here

        // phase 2: read af(mf2,3); stage B(t+2); MFMA acc[2..3][1]
#pragma unroll
        for (int i = 0; i < 2; ++i) {
            af[i][0] = *(const bf16x8*)(A0 + 8192 + i * 4096);
            af[i][1] = *(const bf16x8*)(A1 + 8192 + i * 4096);
            af[i][2] = *(const bf16x8*)(A2 + 8192 + i * 4096);
            af[i][3] = *(const bf16x8*)(A3 + 8192 + i * 4096);
        }
        if (more) STAGE_HALF_B(cur, tkn);
        __builtin_amdgcn_s_barrier();
        __builtin_amdgcn_s_setprio(1);
        MFMA_PH(2, 1)
        __builtin_amdgcn_s_setprio(0);
        __builtin_amdgcn_s_barrier();
        // A-region of buf[cur] read-free from here

        // phase 3: stage A(t+2); MFMA acc[2..3][0]
        if (more) STAGE_HALF_A(cur, tkn);
        __builtin_amdgcn_s_setprio(1);
        MFMA_PH(2, 0)
        __builtin_amdgcn_s_setprio(0);

        // boundary: retire t+1's 8 loads; keep t+2's 8 in flight
        if (more) {
            asm volatile("s_waitcnt vmcnt(8)" ::: "memory");
        } else if (t + 1 < NT) {
            asm volatile("s_waitcnt vmcnt(0)" ::: "memory");
        }
        if (t + 1 < NT) {
            __builtin_amdgcn_s_barrier();
            asm volatile("" ::: "memory");
            __builtin_amdgcn_sched_barrier(0);
        }
    }

    // epilogue: 32x32 C/D: col=lane&31, row=(reg&3)+8*(reg>>2)+4*(lane>>5)
    const int rh = (lane >> 5) * 4;
#pragma unroll
    for (int nf = 0; nf < 2; ++nf) {
        int col = bn + wn * 64 + nf * 32 + l31;
        float bv = bias[col];
#pragma unroll
        for (int mf = 0; mf < 4; ++mf) {
            int rbase = bm + wm * 128 + mf * 32 + rh;
#pragma unroll
            for (int r = 0; r < 16; ++r) {
                int row = rbase + (r & 3) + 8 * (r >> 2);
                C[(size_t)row * NDIM + col] = acc[mf][nf][r] + bv;
            }
        }
    }
#undef STAGE_A
#undef STAGE_B
#undef STAGE_HALF_A
#undef STAGE_HALF_B
#undef MFMA_PH
}

// ---------------- fallback: fp32 vector GEMM (only if ws too small) --------------

__global__ void fallback_gemm(const float* __restrict__ x, const float* __restrict__ W,
                              const float* __restrict__ b, float* __restrict__ out) {
    __shared__ float As[32][32];
    __shared__ float Bs[32][33];
    int tx = threadIdx.x, ty = threadIdx.y;
    int row = blockIdx.y * 32 + ty;
    int col = blockIdx.x * 32 + tx;
    float acc = 0.0f;
    for (int kt = 0; kt < KDIM; kt += 32) {
        As[ty][tx] = x[(size_t)row * KDIM + kt + tx];
        float w = W[(size_t)(kt + ty) * NDIM + col];
        Bs[ty][tx] = (w > 0.0f) ? 1.0f : ((w < 0.0f) ? -1.0f : 0.0f);
        __syncthreads();
#pragma unroll
        for (int k = 0; k < 32; ++k) acc += As[ty][k] * Bs[k][tx];
        __syncthreads();
    }
    out[(size_t)row * NDIM + col] = acc + b[col];
}

// ---------------- launcher ----------------

extern "C" void kernel_launch(void* const* d_in, const int* in_sizes, int n_in,
                              void* d_out, int out_size, void* d_ws, size_t ws_size,
                              hipStream_t stream) {
    const float* x = (const float*)d_in[0];
    const float* W = (const float*)d_in[1];
    const float* b = (const float*)d_in[2];
    float* out = (float*)d_out;

    const size_t need = (size_t)MDIM * KDIM * 2 + (size_t)KDIM * NDIM * 2;  // 64 MB
    if (ws_size >= need) {
        unsigned short* xbf = (unsigned short*)d_ws;
        unsigned short* wqT = xbf + (size_t)MDIM * KDIM;

        prep_x<<<XBLKS, 256, 0, stream>>>(x, xbf);
        prep_w<<<(NDIM / 64) * (KDIM / 64), 256, 0, stream>>>(W, wqT);
        gemm_bf16_bt<<<dim3(NDIM / BN, MDIM / BM), 512, 0, stream>>>(xbf, wqT, b, out);
    } else {
        fallback_gemm<<<dim3(NDIM / 32, MDIM / 32), dim3(32, 32), 0, stream>>>(x, W, b, out);
    }
}

// Round 5
// 284.256 us; speedup vs baseline: 1.0529x; 1.0529x over previous
//
#include <hip/hip_runtime.h>
#include <stdint.h>

#define MDIM 4096
#define NDIM 4096
#define KDIM 4096

#define BM 256
#define BN 256
#define BK 64
#define NT (KDIM / BK)

typedef __attribute__((ext_vector_type(8))) __bf16 bf16x8;
typedef __attribute__((ext_vector_type(4))) float f32x4;
typedef __attribute__((ext_vector_type(8))) unsigned short ushort8_t;
typedef __attribute__((ext_vector_type(4))) unsigned short ushort4_t;

typedef const __attribute__((address_space(1))) void* gas_ptr;
typedef __attribute__((address_space(3))) void* las_ptr;

__device__ __forceinline__ void async_load16(const void* g, void* l) {
    __builtin_amdgcn_global_load_lds((gas_ptr)g, (las_ptr)l, 16, 0, 0);
}

__device__ __forceinline__ unsigned short f32_to_bf16_rne(float f) {
    union { float f; uint32_t u; } v; v.f = f;
    uint32_t u = v.u;
    return (unsigned short)((u + 0x7FFFu + ((u >> 16) & 1u)) >> 16);
}

__device__ __forceinline__ unsigned short sgn_bf16(float w) {
    return (w > 0.f) ? 0x3F80u : ((w < 0.f) ? 0xBF80u : 0u);
}

#define XBLKS 2048

__global__ void prep_kernel(const float* __restrict__ x, const float* __restrict__ W,
                            unsigned short* __restrict__ xbf, unsigned short* __restrict__ wqT) {
    if (blockIdx.x < XBLKS) {
        const int tot8 = MDIM * KDIM / 8;
        int t = blockIdx.x * 256 + threadIdx.x;
        const int stride = XBLKS * 256;
        for (int i = t; i < tot8; i += stride) {
            float4 v0 = ((const float4*)x)[2 * i];
            float4 v1 = ((const float4*)x)[2 * i + 1];
            ushort8_t o;
            o[0] = f32_to_bf16_rne(v0.x); o[1] = f32_to_bf16_rne(v0.y);
            o[2] = f32_to_bf16_rne(v0.z); o[3] = f32_to_bf16_rne(v0.w);
            o[4] = f32_to_bf16_rne(v1.x); o[5] = f32_to_bf16_rne(v1.y);
            o[6] = f32_to_bf16_rne(v1.z); o[7] = f32_to_bf16_rne(v1.w);
            ((ushort8_t*)xbf)[i] = o;
        }
    } else {
        __shared__ __align__(16) unsigned short tile[64][68];
        const int wb = blockIdx.x - XBLKS;
        const int n0 = (wb & 63) * 64;
        const int k0 = (wb >> 6) * 64;
        const int t  = threadIdx.x;
#pragma unroll
        for (int r = 0; r < 2; ++r) {
            int flat = r * 256 + t;
            int k2   = flat >> 4;
            int nch  = (flat & 15) * 4;
            const float* s0 = &W[(size_t)(k0 + 2 * k2) * NDIM + n0 + nch];
            float4 v0 = *(const float4*)(s0);
            float4 v1 = *(const float4*)(s0 + NDIM);
            const float* f0 = (const float*)&v0;
            const float* f1 = (const float*)&v1;
#pragma unroll
            for (int j = 0; j < 4; ++j) {
                union { unsigned short u[2]; unsigned int w; } p;
                p.u[0] = sgn_bf16(f0[j]);
                p.u[1] = sgn_bf16(f1[j]);
                *(unsigned int*)&tile[nch + j][2 * k2] = p.w;
            }
        }
        __syncthreads();
#pragma unroll
        for (int r = 0; r < 2; ++r) {
            int flat = r * 256 + t;
            int n    = flat >> 3;
            int kch  = (flat & 7) * 8;
            ushort4_t a = *(const ushort4_t*)&tile[n][kch];
            ushort4_t b = *(const ushort4_t*)&tile[n][kch + 4];
            ushort8_t o;
            o[0] = a[0]; o[1] = a[1]; o[2] = a[2]; o[3] = a[3];
            o[4] = b[0]; o[5] = b[1]; o[6] = b[2]; o[7] = b[3];
            *(ushort8_t*)&wqT[(size_t)(n0 + n) * KDIM + k0 + kch] = o;
        }
    }
}

// ---- GEMM: R2-verified loop + LDS-slab epilogue (full-128B-line C stores) ----

__global__ __launch_bounds__(512, 2) void gemm_bf16_bt(
        const unsigned short* __restrict__ A,
        const unsigned short* __restrict__ Bt,
        const float* __restrict__ bias,
        float* __restrict__ C)
{
    __shared__ __align__(16) unsigned short lds[2][2][BM * BK];

    const int tid  = threadIdx.x;
    const int wave = tid >> 6;
    const int lane = tid & 63;
    const int wm = wave >> 2;
    const int wn = wave & 3;

    int o   = blockIdx.y * gridDim.x + blockIdx.x;
    int xcd = o & 7, ii = o >> 3;
    int bmi = (xcd >> 1) * 4 + (ii >> 3);
    int bni = (xcd & 1) * 8 + (ii & 7);
    const int bm = bmi * BM;
    const int bn = bni * BN;

    const int lrow = lane >> 3;
    const int lchk = (lane & 7) ^ lrow;
    const size_t aSrc = (size_t)(bm + lrow) * KDIM + lchk * 8;
    const size_t bSrc = (size_t)(bn + lrow) * KDIM + lchk * 8;
    const int g0 = wave * 4;

#define STAGE_A(BUF, TK, G) async_load16(A  + aSrc + (size_t)(G) * (8 * KDIM) + (TK), \
                                         &lds[BUF][0][(G) * 512])
#define STAGE_B(BUF, TK, G) async_load16(Bt + bSrc + (size_t)(G) * (8 * KDIM) + (TK), \
                                         &lds[BUF][1][(G) * 512])

    const int frow = lane & 15;
    const int rb  = frow * 128;
    const int cx0 = ((lane >> 4) ^ (lane & 7)) << 4;
    const int cx1 = cx0 ^ 64;

    const char* L = (const char*)lds;
    const char* aP00 = L +     0 + wm * 16384 + rb + cx0;
    const char* aP01 = L +     0 + wm * 16384 + rb + cx1;
    const char* aP10 = L + 65536 + wm * 16384 + rb + cx0;
    const char* aP11 = L + 65536 + wm * 16384 + rb + cx1;
    const char* bP00 = L + 32768 +         wn * 8192 + rb + cx0;
    const char* bP01 = L + 32768 +         wn * 8192 + rb + cx1;
    const char* bP10 = L + 98304 +         wn * 8192 + rb + cx0;
    const char* bP11 = L + 98304 +         wn * 8192 + rb + cx1;

    f32x4 acc[8][4] = {};
    bf16x8 af[4][2];
    bf16x8 bfr[4][2];

#define MFMA16(MIB, NIB)                                                        \
    _Pragma("unroll")                                                           \
    for (int mi = 0; mi < 4; ++mi)                                              \
        _Pragma("unroll")                                                       \
        for (int ni = 0; ni < 2; ++ni)                                          \
            _Pragma("unroll")                                                   \
            for (int ks = 0; ks < 2; ++ks)                                      \
                acc[(MIB) + mi][(NIB) + ni] =                                   \
                    __builtin_amdgcn_mfma_f32_16x16x32_bf16(                    \
                        af[mi][ks], bfr[(NIB) + ni][ks],                        \
                        acc[(MIB) + mi][(NIB) + ni], 0, 0, 0);

#define STAGE_TILE(BUF, TK)                                      \
    do {                                                         \
        STAGE_A(BUF, TK, g0 + 0); STAGE_A(BUF, TK, g0 + 1);      \
        STAGE_A(BUF, TK, g0 + 2); STAGE_A(BUF, TK, g0 + 3);      \
        STAGE_B(BUF, TK, g0 + 0); STAGE_B(BUF, TK, g0 + 1);      \
        STAGE_B(BUF, TK, g0 + 2); STAGE_B(BUF, TK, g0 + 3);      \
    } while (0)

    STAGE_TILE(0, 0);
    STAGE_TILE(1, BK);
    asm volatile("s_waitcnt vmcnt(8)" ::: "memory");
    __builtin_amdgcn_s_barrier();
    asm volatile("" ::: "memory");
    __builtin_amdgcn_sched_barrier(0);

    for (int t = 0; t < NT; ++t) {
        const bool odd  = t & 1;
        const char* aK0 = odd ? aP10 : aP00;
        const char* aK1 = odd ? aP11 : aP01;
        const char* bK0 = odd ? bP10 : bP00;
        const char* bK1 = odd ? bP11 : bP01;
        const int  cur  = odd ? 1 : 0;

#pragma unroll
        for (int mi = 0; mi < 4; ++mi) {
            af[mi][0] = *(const bf16x8*)(aK0 + mi * 2048);
            af[mi][1] = *(const bf16x8*)(aK1 + mi * 2048);
        }
#pragma unroll
        for (int ni = 0; ni < 2; ++ni) {
            bfr[ni][0] = *(const bf16x8*)(bK0 + ni * 2048);
            bfr[ni][1] = *(const bf16x8*)(bK1 + ni * 2048);
        }
        __builtin_amdgcn_s_barrier();
        __builtin_amdgcn_s_setprio(1);
        MFMA16(0, 0)
        __builtin_amdgcn_s_setprio(0);
        __builtin_amdgcn_s_barrier();

#pragma unroll
        for (int ni = 2; ni < 4; ++ni) {
            bfr[ni][0] = *(const bf16x8*)(bK0 + ni * 2048);
            bfr[ni][1] = *(const bf16x8*)(bK1 + ni * 2048);
        }
        __builtin_amdgcn_s_barrier();
        __builtin_amdgcn_s_setprio(1);
        MFMA16(0, 2)
        __builtin_amdgcn_s_setprio(0);
        __builtin_amdgcn_s_barrier();

#pragma unroll
        for (int mi = 0; mi < 4; ++mi) {
            af[mi][0] = *(const bf16x8*)(aK0 + 8192 + mi * 2048);
            af[mi][1] = *(const bf16x8*)(aK1 + 8192 + mi * 2048);
        }
        __builtin_amdgcn_s_barrier();
        __builtin_amdgcn_s_setprio(1);
        MFMA16(4, 2)
        __builtin_amdgcn_s_setprio(0);
        __builtin_amdgcn_s_barrier();

        if (t + 2 < NT) {
            STAGE_TILE(cur, (t + 2) * BK);
        }
        __builtin_amdgcn_s_setprio(1);
        MFMA16(4, 0)
        __builtin_amdgcn_s_setprio(0);

        if (t + 2 < NT) {
            asm volatile("s_waitcnt vmcnt(8)" ::: "memory");
        } else if (t + 1 < NT) {
            asm volatile("s_waitcnt vmcnt(0)" ::: "memory");
        }
        if (t + 1 < NT) {
            __builtin_amdgcn_s_barrier();
            asm volatile("" ::: "memory");
            __builtin_amdgcn_sched_barrier(0);
        }
    }

    // ---- epilogue: 4 slabs of 64 rows x 256 cols through LDS (pad 260) ----
    // Wave (wm,wn) owns C rows [wm*128 + mig*16 ...], cols [wn*64 ...].
    // Slab s covers local rows [s*64, s*64+64): written by the 4 waves with
    // wm == s>>1 using their m-frags mig in {4*(s&1) .. 4*(s&1)+3}.
    // Readback: all 8 waves, 8 rows each, 32 lanes x 16B = 512B... row = 1024B:
    // 64 lanes cover one row (lane*16B), full 128B lines.
    float* cls = (float*)&lds[0][0][0];     // [64][260] f32 = 66.6 KB
    const int rquad = (lane >> 4) * 4;
#pragma unroll
    for (int s = 0; s < 4; ++s) {
        __syncthreads();                    // slab s-1 fully read / K-loop done
        if (wm == (s >> 1)) {
            const int mb = (s & 1) * 4;     // m-frag base for this slab
#pragma unroll
            for (int ni = 0; ni < 4; ++ni) {
                int lc = wn * 64 + ni * 16 + frow;          // 0..255
                float bv = bias[bn + lc];
#pragma unroll
                for (int mi = 0; mi < 4; ++mi) {
                    int lr = mi * 16 + rquad;               // 0..63 within slab
#pragma unroll
                    for (int r = 0; r < 4; ++r)
                        cls[(size_t)(lr + r) * 260 + lc] = acc[mb + mi][ni][r] + bv;
                }
            }
        }
        __syncthreads();
        // readback: 512 threads, 64 rows x 1024B; one row per 64-lane wave pass
        {
            const int c4 = lane * 4;                        // 0..252
#pragma unroll
            for (int p = 0; p < 8; ++p) {
                int row = wave * 8 + p;                     // 0..63 within slab
                f32x4 v = *(const f32x4*)&cls[(size_t)row * 260 + c4];
                *(f32x4*)&C[(size_t)(bm + s * 64 + row) * NDIM + bn + c4] = v;
            }
        }
    }
#undef STAGE_A
#undef STAGE_B
#undef STAGE_TILE
#undef MFMA16
}

__global__ void fallback_gemm(const float* __restrict__ x, const float* __restrict__ W,
                              const float* __restrict__ b, float* __restrict__ out) {
    __shared__ float As[32][32];
    __shared__ float Bs[32][33];
    int tx = threadIdx.x, ty = threadIdx.y;
    int row = blockIdx.y * 32 + ty;
    int col = blockIdx.x * 32 + tx;
    float acc = 0.0f;
    for (int kt = 0; kt < KDIM; kt += 32) {
        As[ty][tx] = x[(size_t)row * KDIM + kt + tx];
        float w = W[(size_t)(kt + ty) * NDIM + col];
        Bs[ty][tx] = (w > 0.0f) ? 1.0f : ((w < 0.0f) ? -1.0f : 0.0f);
        __syncthreads();
#pragma unroll
        for (int k = 0; k < 32; ++k) acc += As[ty][k] * Bs[k][tx];
        __syncthreads();
    }
    out[(size_t)row * NDIM + col] = acc + b[col];
}

extern "C" void kernel_launch(void* const* d_in, const int* in_sizes, int n_in,
                              void* d_out, int out_size, void* d_ws, size_t ws_size,
                              hipStream_t stream) {
    const float* x = (const float*)d_in[0];
    const float* W = (const float*)d_in[1];
    const float* b = (const float*)d_in[2];
    float* out = (float*)d_out;

    const size_t need = (size_t)MDIM * KDIM * 2 + (size_t)KDIM * NDIM * 2;
    if (ws_size >= need) {
        unsigned short* xbf = (unsigned short*)d_ws;
        unsigned short* wqT = xbf + (size_t)MDIM * KDIM;
        prep_kernel<<<XBLKS + (NDIM / 64) * (KDIM / 64), 256, 0, stream>>>(x, W, xbf, wqT);
        gemm_bf16_bt<<<dim3(NDIM / BN, MDIM / BM), 512, 0, stream>>>(xbf, wqT, b, out);
    } else {
        fallback_gemm<<<dim3(NDIM / 32, MDIM / 32), dim3(32, 32), 0, stream>>>(x, W, b, out);
    }
}